// Round 8
// baseline (438.848 us; speedup 1.0000x reference)
//
#include <hip/hip_runtime.h>

#define QLEN 512
#define KLEN 1024
#define BATCH 8
#define HEADS 16
#define HDIM 64
#define EMBED 1024

typedef __attribute__((ext_vector_type(4))) float f32x4;
typedef __attribute__((ext_vector_type(8))) short short8;
typedef unsigned short ushort_t;
typedef unsigned char uchar_t;
typedef unsigned int uint_t;

#define MFMA16(a, b, c) __builtin_amdgcn_mfma_f32_16x16x32_bf16((a), (b), (c), 0, 0, 0)

__device__ __forceinline__ float b2f(ushort_t u) {
    union { uint_t i; float f; } c; c.i = ((uint_t)u) << 16; return c.f;
}
__device__ __forceinline__ ushort_t f2b(float x) {
    union { float f; uint_t i; } c; c.f = x;
    uint_t u = c.i;
    uint_t r = (u + 0x7FFFu + ((u >> 16) & 1u)) >> 16;
    return (ushort_t)r;
}
__device__ __forceinline__ uint_t pk2(float lo, float hi) {
    return (uint_t)f2b(lo) | ((uint_t)f2b(hi) << 16);
}
// load a "float" that may be stored as f32 or bf16
__device__ __forceinline__ float ldf(const void* p, int idx, int f32m) {
    if (f32m) return ((const float*)p)[idx];
    return b2f(((const ushort_t*)p)[idx]);
}

typedef const __attribute__((address_space(1))) void async_src_t;
typedef __attribute__((address_space(3))) void async_dst_t;

// ---------------- dtype detector ----------------
// flags[0]: 1 if float tensors are f32, 0 if bf16
// flags[1]: mask mode: 0=int32, 1=uint8, 2=bf16, 3=f32
__global__ __launch_bounds__(256) void detect_kernel(const void* mask, const void* pad, int* flags) {
    __shared__ int cnt[4];
    int tid = threadIdx.x;
    if (tid < 4) cnt[tid] = 0;
    __syncthreads();
    const uchar_t* mb = (const uchar_t*)mask;
    const uchar_t* pb = (const uchar_t*)pad;
    int lnz1 = 0, l3f1 = 0, l3f3 = 0, lpnz = 0;
    for (int off = tid; off < 4096; off += 256) {
        uchar_t v = mb[off];
        int m4 = off & 3;
        if (m4 != 0 && v != 0) lnz1++;
        if (m4 == 1 && v == 0x3F) l3f1++;
        if (m4 == 3 && v == 0x3F) l3f3++;
        uchar_t p = pb[off];
        if (m4 == 0 && p != 0) lpnz++;
    }
    atomicAdd(&cnt[0], lnz1); atomicAdd(&cnt[1], l3f1);
    atomicAdd(&cnt[2], l3f3); atomicAdd(&cnt[3], lpnz);
    __syncthreads();
    if (tid == 0) {
        flags[0] = (cnt[3] == 0) ? 1 : 0;
        int mm;
        if (cnt[0] == 0) mm = 0;
        else if (cnt[1] > 16) mm = 2;
        else if (cnt[2] > 16) mm = 3;
        else mm = 1;
        flags[1] = mm;
    }
}

// ---------------- bulk convert to bf16 (pk2-based, no inline asm) ----------------
__global__ __launch_bounds__(256) void convert_kernel(const void* __restrict__ src,
                                                      ushort_t* __restrict__ dst,
                                                      int n8, const int* flags) {
    int i = blockIdx.x * 256 + threadIdx.x;
    if (i >= n8) return;
    if (flags[0]) {
        const float4* s = (const float4*)src + (size_t)i * 2;
        float4 a = s[0], b = s[1];
        uint4 o;
        o.x = pk2(a.x, a.y); o.y = pk2(a.z, a.w);
        o.z = pk2(b.x, b.y); o.w = pk2(b.z, b.w);
        ((uint4*)dst)[i] = o;
    } else {
        ((uint4*)dst)[i] = ((const uint4*)src)[i];
    }
}

// ---------------- weight transpose (to bf16 W^T) ----------------
__global__ __launch_bounds__(256) void transpose_kernel(
    const void* W0, const void* W1, const void* W2, const void* W3, const void* W4,
    ushort_t* T0, ushort_t* T1, ushort_t* T2, ushort_t* T3, ushort_t* T4,
    const int* flags) {
    __shared__ float tl[32][33];
    int f32m = flags[0];
    const void* W; ushort_t* T;
    switch (blockIdx.z) {
        case 0: W = W0; T = T0; break;
        case 1: W = W1; T = T1; break;
        case 2: W = W2; T = T2; break;
        case 3: W = W3; T = T3; break;
        default: W = W4; T = T4; break;
    }
    int tx = threadIdx.x, ty = threadIdx.y;  // (32,8)
    int x = blockIdx.x * 32 + tx;
    #pragma unroll
    for (int j = 0; j < 4; ++j) {
        int row = blockIdx.y * 32 + ty + j * 8;
        tl[ty + j * 8][tx] = ldf(W, row * 1024 + x, f32m);
    }
    __syncthreads();
    #pragma unroll
    for (int j = 0; j < 4; ++j) {
        int n = blockIdx.x * 32 + ty + j * 8;
        T[n * 1024 + blockIdx.y * 32 + tx] = f2b(tl[tx][ty + j * 8]);
    }
}

// ---------------- V transpose: vh[bh][k][d] -> vT[bh][d][k] ----------------
__global__ __launch_bounds__(256) void vtrans_kernel(const ushort_t* __restrict__ vh,
                                                     ushort_t* __restrict__ vT) {
    __shared__ ushort_t t[64][68];
    int bh = blockIdx.y;
    int k0 = blockIdx.x * 64;
    int tid = threadIdx.x;
    int r = tid >> 2, c0 = (tid & 3) * 16;
    const short8* src = (const short8*)&vh[((size_t)bh * 1024 + k0 + r) * 64 + c0];
    *(short8*)&t[r][c0] = src[0];
    *(short8*)&t[r][c0 + 8] = src[1];
    __syncthreads();
    ushort_t tmp[16];
    #pragma unroll
    for (int j = 0; j < 16; ++j) tmp[j] = t[c0 + j][r];
    short8* dst = (short8*)&vT[((size_t)bh * 64 + r) * 1024 + k0 + c0];
    dst[0] = *(short8*)&tmp[0];
    dst[1] = *(short8*)&tmp[8];
}

// ---------------- projection GEMM (global_load_lds, linear LDS) ----------------
// EPI 0: qU/qV (adds bq then U/V, layout (b,h,q,d))
// EPI 1: k/v proj (adds bias, layout (b,h,kk,d))
// EPI 2: R proj (no bias, layout (h,j,d));  a_mode=1: A may be f32 (scalar staging)
// EPI 3: out proj (adds bias, writes d_out (q,b,e), dtype per flag)
template<int EPI>
__global__ __launch_bounds__(256) void gemm_kernel(
    const void* Av, const ushort_t* BT, int M,
    const void* bias, const void* Up, const void* Vp,
    void* out0, void* out1, const int* flags, int a_mode) {
    __shared__ ushort_t As[4096];
    __shared__ ushort_t Bs[4096];
    const int f32m = flags[0];
    const int a_f32 = a_mode ? f32m : 0;
    const int tid = threadIdx.x;
    const int wid = tid >> 6, lane = tid & 63;
    const int wr = (wid >> 1) * 64, wc = (wid & 1) * 64;
    const int m0 = blockIdx.x * 128, n0 = blockIdx.y * 128;
    const int ch0 = wid * 2;
    const int lrow = lane >> 2, lcol = (lane & 3) * 8;

    f32x4 acc[4][4];
    #pragma unroll
    for (int m = 0; m < 4; ++m)
        #pragma unroll
        for (int n = 0; n < 4; ++n)
            acc[m][n] = (f32x4){0.f, 0.f, 0.f, 0.f};

    for (int k0 = 0; k0 < 1024; k0 += 32) {
        if (a_f32) {
            const float* Af = (const float*)Av + (size_t)(m0 + (tid >> 1)) * 1024 + k0 + (tid & 1) * 16;
            ushort_t* dst = &As[(tid >> 1) * 32 + (tid & 1) * 16];
            #pragma unroll
            for (int e = 0; e < 16; ++e) dst[e] = f2b(Af[e]);
        } else {
            #pragma unroll
            for (int t = 0; t < 2; ++t) {
                int ch = ch0 + t;
                const ushort_t* ga = (const ushort_t*)Av + (size_t)(m0 + ch * 16 + lrow) * 1024 + k0 + lcol;
                __builtin_amdgcn_global_load_lds((async_src_t*)ga, (async_dst_t*)&As[ch * 512], 16, 0, 0);
            }
        }
        #pragma unroll
        for (int t = 0; t < 2; ++t) {
            int ch = ch0 + t;
            const ushort_t* gb = BT + (size_t)(n0 + ch * 16 + lrow) * 1024 + k0 + lcol;
            __builtin_amdgcn_global_load_lds((async_src_t*)gb, (async_dst_t*)&Bs[ch * 512], 16, 0, 0);
        }
        __syncthreads();

        short8 af[4], bf[4];
        #pragma unroll
        for (int m = 0; m < 4; ++m)
            af[m] = *(const short8*)&As[(wr + m * 16 + (lane & 15)) * 32 + (lane >> 4) * 8];
        #pragma unroll
        for (int n = 0; n < 4; ++n)
            bf[n] = *(const short8*)&Bs[(wc + n * 16 + (lane & 15)) * 32 + (lane >> 4) * 8];
        #pragma unroll
        for (int m = 0; m < 4; ++m)
            #pragma unroll
            for (int n = 0; n < 4; ++n)
                acc[m][n] = MFMA16(af[m], bf[n], acc[m][n]);
        __syncthreads();
    }

    #pragma unroll
    for (int n = 0; n < 4; ++n) {
        int gn = n0 + wc + n * 16 + (lane & 15);
        float bv_ = (EPI == 2) ? 0.f : ldf(bias, gn, f32m);
        float uu = 0.f, vv = 0.f;
        if (EPI == 0) { uu = ldf(Up, gn, f32m); vv = ldf(Vp, gn, f32m); }
        #pragma unroll
        for (int m = 0; m < 4; ++m) {
            #pragma unroll
            for (int j = 0; j < 4; ++j) {
                int gm = m0 + wr + m * 16 + (lane >> 4) * 4 + j;
                float c = acc[m][n][j] + bv_;
                if (EPI == 0) {
                    int q = gm >> 3, b = gm & 7;
                    int h = gn >> 6, d = gn & 63;
                    int idx = ((b * 16 + h) * 512 + q) * 64 + d;
                    ((ushort_t*)out0)[idx] = f2b(c + uu);
                    ((ushort_t*)out1)[idx] = f2b(c + vv);
                } else if (EPI == 1) {
                    int kk = gm >> 3, b = gm & 7;
                    int h = gn >> 6, d = gn & 63;
                    ((ushort_t*)out0)[((b * 16 + h) * 1024 + kk) * 64 + d] = f2b(c);
                } else if (EPI == 2) {
                    int h = gn >> 6, d = gn & 63;
                    ((ushort_t*)out0)[(h * 1024 + gm) * 64 + d] = f2b(c);
                } else {
                    if (f32m) ((float*)out0)[gm * 1024 + gn] = c;
                    else ((ushort_t*)out0)[gm * 1024 + gn] = f2b(c);
                }
            }
        }
    }
}

// ---------------- fused attention (S^T layout, LDS-staged P for PV, 8 waves) ----------------
// block: 16 q-rows x one (b,h); 8 waves, wave w owns k in [w*128, w*128+128)
// Lane: c = lane&15 = q-column, g = lane>>4. S^T C-layout: col=c(q), row=k-local.
#define SP_STR 1032   // sPos row stride (ushorts): 516 words % 32 = 4 -> 2-way banks
#define PB_STR 144    // sPb row stride (ushorts): 72 words % 32 = 8 -> uniform b128 packing
__global__ __launch_bounds__(512, 4) void attn_kernel(
    const ushort_t* __restrict__ qU, const ushort_t* __restrict__ qV,
    const ushort_t* __restrict__ kh, const ushort_t* __restrict__ vT,
    const ushort_t* __restrict__ Rl, const void* __restrict__ mask,
    const void* __restrict__ pad, ushort_t* __restrict__ alpha, const int* flags) {

    // union region: sPos [17][1032] u16 (35,088 B)  |  sPb [8][16][144] u16 (36,864 B)
    //             | sO [8][1088] f32 (34,816 B).  Aliasing is barrier-separated.
    __shared__ __align__(16) uchar_t uni[36864];
    ushort_t* sPos = (ushort_t*)uni;
    ushort_t* sPb  = (ushort_t*)uni;
    float*    sO   = (float*)uni;
    __shared__ float spad[512];
    __shared__ float sred[2][8][16];
    __shared__ float ssinv[16];

    const int tid = threadIdx.x;
    const int wid = tid >> 6, lane = tid & 63;
    const int g = lane >> 4, c = lane & 15;
    const int q0 = blockIdx.x * 16;
    const int bh = blockIdx.y;
    const int b = bh >> 4, h = bh & 15;
    const int f32m = flags[0], mm = flags[1];
    const int kbase = wid * 128;

    if (tid < 512) spad[tid] = ldf(pad, b * 512 + tid, f32m);

    // ---- position: PR^T[j][q] = R[j] . qV[q];  write PR[q][j] (bf16) to sPos
    {
        const ushort_t* qvap = qV + ((size_t)bh * 512 + q0 + c) * 64 + g * 8;
        short8 bva0 = *(const short8*)qvap;
        short8 bva1 = *(const short8*)(qvap + 32);
        int qvbq = q0 + 16 + c; if (qvbq > 511) qvbq = 511;
        const ushort_t* qvbp = qV + ((size_t)bh * 512 + qvbq) * 64 + g * 8;
        short8 bvb0 = *(const short8*)qvbp;
        short8 bvb1 = *(const short8*)(qvbp + 32);
        #pragma unroll
        for (int m = 0; m < 8; ++m) {
            const ushort_t* rp = Rl + ((size_t)h * 1024 + kbase + m * 16 + c) * 64 + g * 8;
            short8 ra0 = *(const short8*)rp;
            short8 ra1 = *(const short8*)(rp + 32);
            f32x4 p0 = (f32x4){0.f, 0.f, 0.f, 0.f};
            p0 = MFMA16(ra0, bva0, p0);
            p0 = MFMA16(ra1, bva1, p0);
            f32x4 p1 = (f32x4){0.f, 0.f, 0.f, 0.f};
            p1 = MFMA16(ra0, bvb0, p1);
            p1 = MFMA16(ra1, bvb1, p1);
            uint2 w;
            w.x = pk2(p0[0], p0[1]);
            w.y = pk2(p0[2], p0[3]);
            *(uint2*)&sPos[c * SP_STR + kbase + m * 16 + g * 4] = w;
            if (c == 0) {
                uint2 x;
                x.x = pk2(p1[0], p1[1]);
                x.y = pk2(p1[2], p1[3]);
                *(uint2*)&sPos[16 * SP_STR + kbase + m * 16 + g * 4] = x;
            }
        }
    }

    // ---- content: S^T[k][q] = K[k] . qU[q]
    f32x4 acc[8];
    {
        const ushort_t* qup = qU + ((size_t)bh * 512 + q0 + c) * 64 + g * 8;
        short8 bu0 = *(const short8*)qup;
        short8 bu1 = *(const short8*)(qup + 32);
        #pragma unroll
        for (int m = 0; m < 8; ++m) {
            const ushort_t* kp = kh + ((size_t)bh * 1024 + kbase + m * 16 + c) * 64 + g * 8;
            short8 ka0 = *(const short8*)kp;
            short8 ka1 = *(const short8*)(kp + 32);
            f32x4 t = (f32x4){0.f, 0.f, 0.f, 0.f};
            t = MFMA16(ka0, bu0, t);
            t = MFMA16(ka1, bu1, t);
            acc[m] = t;
        }
    }
    __syncthreads();

    // ---- score: add rel-shifted position (sPos gather), scale, masks
    const int q = q0 + c;
    const float padq = spad[q];
    float mx = -3.0e38f;
    #pragma unroll
    for (int m = 0; m < 8; ++m) {
        int k0e = kbase + m * 16 + g * 4;
        uint_t mb[4];
        if (mm == 1) {
            uint_t w = *(const uint_t*)((const uchar_t*)mask + (size_t)q * 1024 + k0e);
            mb[0] = w & 0xFFu; mb[1] = w & 0xFF00u; mb[2] = w & 0xFF0000u; mb[3] = w & 0xFF000000u;
        } else if (mm == 2) {
            uint2 w = *(const uint2*)((const ushort_t*)mask + (size_t)q * 1024 + k0e);
            mb[0] = w.x & 0xFFFFu; mb[1] = w.x >> 16; mb[2] = w.y & 0xFFFFu; mb[3] = w.y >> 16;
        } else {
            uint4 w = *(const uint4*)((const uint_t*)mask + (size_t)q * 1024 + k0e);
            mb[0] = w.x; mb[1] = w.y; mb[2] = w.z; mb[3] = w.w;
        }
        #pragma unroll
        for (int jj = 0; jj < 4; ++jj) {
            int k = k0e + jj;
            int delta = k - q;
            int wrap = (delta > 512) ? 1 : 0;
            int j = wrap ? (delta - 514) : (delta + 511);
            float pos = b2f(sPos[(c + wrap) * SP_STR + (j < 0 ? 0 : j)]);
            if (delta == 513) pos = 0.f;
            float s = (acc[m][jj] + pos) * 0.03125f;
            bool dead = (mb[jj] != 0);
            if (k >= 512) {
                float padk = spad[k - 512];
                if (padq == 0.f || padk == 0.f) dead = true;
            }
            if (dead) s = -1e20f;
            acc[m][jj] = s;
            mx = fmaxf(mx, s);
        }
    }
    // row-max: lanes sharing q are xor-16/32 apart; then cross-wave
    mx = fmaxf(mx, __shfl_xor(mx, 16, 64));
    mx = fmaxf(mx, __shfl_xor(mx, 32, 64));
    if (lane < 16) sred[0][wid][c] = mx;
    __syncthreads();   // also: all sPos reads complete before sPb overlays it
    {
        float a0 = fmaxf(fmaxf(sred[0][0][c], sred[0][1][c]), fmaxf(sred[0][2][c], sred[0][3][c]));
        float a1 = fmaxf(fmaxf(sred[0][4][c], sred[0][5][c]), fmaxf(sred[0][6][c], sred[0][7][c]));
        mx = fmaxf(a0, a1);
    }

    // ---- exp + pack P (bf16) into per-wave LDS tile sPb[wid][c][k_local]
    float ls = 0.f;
    #pragma unroll
    for (int m = 0; m < 8; ++m) {
        float p0 = __expf(acc[m][0] - mx);
        float p1 = __expf(acc[m][1] - mx);
        float p2 = __expf(acc[m][2] - mx);
        float p3 = __expf(acc[m][3] - mx);
        ls += (p0 + p1) + (p2 + p3);
        uint2 w;
        w.x = pk2(p0, p1);
        w.y = pk2(p2, p3);
        *(uint2*)&sPb[(wid * 16 + c) * PB_STR + m * 16 + g * 4] = w;
    }
    ls += __shfl_xor(ls, 16, 64);
    ls += __shfl_xor(ls, 32, 64);
    if (lane < 16) sred[1][wid][c] = ls;
    __syncthreads();   // sPb writes visible; all waves' P staged
    {
        float a0 = (sred[1][0][c] + sred[1][1][c]) + (sred[1][2][c] + sred[1][3][c]);
        float a1 = (sred[1][4][c] + sred[1][5][c]) + (sred[1][6][c] + sred[1][7][c]);
        ls = a0 + a1;
    }
    if (wid == 0 && lane < 16) ssinv[c] = 1.0f / ls;

    // ---- PV: O^T[d][q] = sum_k V^T[d][k] P^T[k][q]; B-frags via ds_read_b128
    f32x4 oacc[4];
    #pragma unroll
    for (int dm = 0; dm < 4; ++dm) oacc[dm] = (f32x4){0.f, 0.f, 0.f, 0.f};
    #pragma unroll
    for (int ch = 0; ch < 4; ++ch) {
        short8 pb = *(const short8*)&sPb[(wid * 16 + c) * PB_STR + ch * 32 + g * 8];
        #pragma unroll
        for (int dm = 0; dm < 4; ++dm) {
            const ushort_t* vp = vT + ((size_t)bh * 64 + dm * 16 + c) * 1024 + kbase + ch * 32 + g * 8;
            short8 va = *(const short8*)vp;
            oacc[dm] = MFMA16(va, pb, oacc[dm]);
        }
    }

    // cross-wave O reduction (overlay sO on union region; PV sPb reads done)
    __syncthreads();
    #pragma unroll
    for (int dm = 0; dm < 4; ++dm)
        #pragma unroll
        for (int jj = 0; jj < 4; ++jj)
            sO[wid * 1088 + (dm * 16 + g * 4 + jj) * 17 + c] = oacc[dm][jj];
    __syncthreads();
    for (int e = tid; e < 1024; e += 512) {
        int d = e & 63, qq = e >> 6;
        float v = ((sO[d * 17 + qq] + sO[1088 + d * 17 + qq]) +
                   (sO[2176 + d * 17 + qq] + sO[3264 + d * 17 + qq])) +
                  ((sO[4352 + d * 17 + qq] + sO[5440 + d * 17 + qq]) +
                   (sO[6528 + d * 17 + qq] + sO[7616 + d * 17 + qq]));
        v *= ssinv[qq];
        alpha[((size_t)(q0 + qq) * 8 + b) * 1024 + h * 64 + d] = f2b(v);
    }
}

// ---------------- launcher ----------------
// Workspace: EXACTLY 88,081,408 bytes (round-3/6/7 proven footprint), r7 alias scheme.
extern "C" void kernel_launch(void* const* d_in, const int* in_sizes, int n_in,
                              void* d_out, int out_size, void* d_ws, size_t ws_size,
                              hipStream_t stream) {
    char* ws = (char*)d_ws;
    int* flags = (int*)ws;
    ushort_t* WqT   = (ushort_t*)(ws + 1024);
    ushort_t* WkT   = WqT + 1048576;
    ushort_t* WvT   = WkT + 1048576;
    ushort_t* WposT = WvT + 1048576;
    ushort_t* WoT   = WposT + 1048576;
    ushort_t* qUw   = WoT + 1048576;            // 4,194,304
    ushort_t* qVw   = qUw + 4194304;            // 4,194,304
    ushort_t* khw   = qVw + 4194304;            // 8,388,608
    ushort_t* Rlw   = khw + 8388608;            // 1,048,576
    ushort_t* R1    = Rlw + 1048576;            // 4,194,304
    ushort_t* R2    = R1 + 4194304;             // 8,388,608
    ushort_t* R3    = R2 + 8388608;             // 8,388,608
    // aliases (lifetime-disjoint, stream-ordered):
    ushort_t* qbf = R1;     // convert out -> read by qGEMM -> dead
    ushort_t* alw = R1;     // attn out -> read by outGEMM
    ushort_t* kbf = R2;     // convert out -> read by kGEMM -> dead
    ushort_t* vhw = R2;     // vGEMM out -> read by vtrans -> dead
    ushort_t* vbf = R3;     // convert out -> read by vGEMM -> dead
    ushort_t* vTw = R3;     // vtrans out -> read by attn

    detect_kernel<<<1, 256, 0, stream>>>(d_in[6], d_in[7], flags);
    // bulk input conversion to bf16 (query, key, value)
    convert_kernel<<<2048, 256, 0, stream>>>(d_in[0], qbf, 524288, flags);
    convert_kernel<<<4096, 256, 0, stream>>>(d_in[1], kbf, 1048576, flags);
    convert_kernel<<<4096, 256, 0, stream>>>(d_in[2], vbf, 1048576, flags);
    // weight transposes
    transpose_kernel<<<dim3(32, 32, 5), dim3(32, 8), 0, stream>>>(
        d_in[8], d_in[10], d_in[12], d_in[14], d_in[15],
        WqT, WkT, WvT, WposT, WoT, flags);
    // q projection -> qU, qV (fast A path)
    gemm_kernel<0><<<dim3(32, 8), 256, 0, stream>>>(qbf, WqT, 4096, d_in[9], d_in[4], d_in[5], qUw, qVw, flags, 0);
    // k, v projections (fast A path)
    gemm_kernel<1><<<dim3(64, 8), 256, 0, stream>>>(kbf, WkT, 8192, d_in[11], nullptr, nullptr, khw, nullptr, flags, 0);
    gemm_kernel<1><<<dim3(64, 8), 256, 0, stream>>>(vbf, WvT, 8192, d_in[13], nullptr, nullptr, vhw, nullptr, flags, 0);
    // R projection (raw pos_embedding, scalar-convert staging when f32)
    gemm_kernel<2><<<dim3(8, 8), 256, 0, stream>>>(d_in[3], WposT, 1024, nullptr, nullptr, nullptr, Rlw, nullptr, flags, 1);
    // V transpose for PV A-operand: R2 -> R3
    vtrans_kernel<<<dim3(16, 128), 256, 0, stream>>>(vhw, vTw);
    // fused attention (8 waves/block, LDS-staged P)
    attn_kernel<<<dim3(32, 128), 512, 0, stream>>>(qUw, qVw, khw, vTw, Rlw, d_in[6], d_in[7], alw, flags);
    // output projection
    gemm_kernel<3><<<dim3(32, 8), 256, 0, stream>>>(alw, WoT, 4096, d_in[16], nullptr, nullptr, d_out, nullptr, flags, 0);
}

// Round 9
// 431.299 us; speedup vs baseline: 1.0175x; 1.0175x over previous
//
#include <hip/hip_runtime.h>

#define QLEN 512
#define KLEN 1024
#define BATCH 8
#define HEADS 16
#define HDIM 64
#define EMBED 1024

typedef __attribute__((ext_vector_type(4))) float f32x4;
typedef __attribute__((ext_vector_type(8))) short short8;
typedef unsigned short ushort_t;
typedef unsigned char uchar_t;
typedef unsigned int uint_t;

#define MFMA16(a, b, c) __builtin_amdgcn_mfma_f32_16x16x32_bf16((a), (b), (c), 0, 0, 0)

__device__ __forceinline__ float b2f(ushort_t u) {
    union { uint_t i; float f; } c; c.i = ((uint_t)u) << 16; return c.f;
}
__device__ __forceinline__ ushort_t f2b(float x) {
    union { float f; uint_t i; } c; c.f = x;
    uint_t u = c.i;
    uint_t r = (u + 0x7FFFu + ((u >> 16) & 1u)) >> 16;
    return (ushort_t)r;
}
__device__ __forceinline__ uint_t pk2(float lo, float hi) {
    return (uint_t)f2b(lo) | ((uint_t)f2b(hi) << 16);
}
// load a "float" that may be stored as f32 or bf16
__device__ __forceinline__ float ldf(const void* p, int idx, int f32m) {
    if (f32m) return ((const float*)p)[idx];
    return b2f(((const ushort_t*)p)[idx]);
}

typedef const __attribute__((address_space(1))) void async_src_t;
typedef __attribute__((address_space(3))) void async_dst_t;

// ---------------- dtype detector ----------------
// flags[0]: 1 if float tensors are f32, 0 if bf16
// flags[1]: mask mode: 0=int32, 1=uint8, 2=bf16, 3=f32
__global__ __launch_bounds__(256) void detect_kernel(const void* mask, const void* pad, int* flags) {
    __shared__ int cnt[4];
    int tid = threadIdx.x;
    if (tid < 4) cnt[tid] = 0;
    __syncthreads();
    const uchar_t* mb = (const uchar_t*)mask;
    const uchar_t* pb = (const uchar_t*)pad;
    int lnz1 = 0, l3f1 = 0, l3f3 = 0, lpnz = 0;
    for (int off = tid; off < 4096; off += 256) {
        uchar_t v = mb[off];
        int m4 = off & 3;
        if (m4 != 0 && v != 0) lnz1++;
        if (m4 == 1 && v == 0x3F) l3f1++;
        if (m4 == 3 && v == 0x3F) l3f3++;
        uchar_t p = pb[off];
        if (m4 == 0 && p != 0) lpnz++;
    }
    atomicAdd(&cnt[0], lnz1); atomicAdd(&cnt[1], l3f1);
    atomicAdd(&cnt[2], l3f3); atomicAdd(&cnt[3], lpnz);
    __syncthreads();
    if (tid == 0) {
        flags[0] = (cnt[3] == 0) ? 1 : 0;
        int mm;
        if (cnt[0] == 0) mm = 0;
        else if (cnt[1] > 16) mm = 2;
        else if (cnt[2] > 16) mm = 3;
        else mm = 1;
        flags[1] = mm;
    }
}

// ---------------- bulk convert to bf16 (pk2-based, no inline asm) ----------------
__global__ __launch_bounds__(256) void convert_kernel(const void* __restrict__ src,
                                                      ushort_t* __restrict__ dst,
                                                      int n8, const int* flags) {
    int i = blockIdx.x * 256 + threadIdx.x;
    if (i >= n8) return;
    if (flags[0]) {
        const float4* s = (const float4*)src + (size_t)i * 2;
        float4 a = s[0], b = s[1];
        uint4 o;
        o.x = pk2(a.x, a.y); o.y = pk2(a.z, a.w);
        o.z = pk2(b.x, b.y); o.w = pk2(b.z, b.w);
        ((uint4*)dst)[i] = o;
    } else {
        ((uint4*)dst)[i] = ((const uint4*)src)[i];
    }
}

// ---------------- weight transpose (to bf16 W^T) ----------------
__global__ __launch_bounds__(256) void transpose_kernel(
    const void* W0, const void* W1, const void* W2, const void* W3, const void* W4,
    ushort_t* T0, ushort_t* T1, ushort_t* T2, ushort_t* T3, ushort_t* T4,
    const int* flags) {
    __shared__ float tl[32][33];
    int f32m = flags[0];
    const void* W; ushort_t* T;
    switch (blockIdx.z) {
        case 0: W = W0; T = T0; break;
        case 1: W = W1; T = T1; break;
        case 2: W = W2; T = T2; break;
        case 3: W = W3; T = T3; break;
        default: W = W4; T = T4; break;
    }
    int tx = threadIdx.x, ty = threadIdx.y;  // (32,8)
    int x = blockIdx.x * 32 + tx;
    #pragma unroll
    for (int j = 0; j < 4; ++j) {
        int row = blockIdx.y * 32 + ty + j * 8;
        tl[ty + j * 8][tx] = ldf(W, row * 1024 + x, f32m);
    }
    __syncthreads();
    #pragma unroll
    for (int j = 0; j < 4; ++j) {
        int n = blockIdx.x * 32 + ty + j * 8;
        T[n * 1024 + blockIdx.y * 32 + tx] = f2b(tl[tx][ty + j * 8]);
    }
}

// ---------------- V transpose: vh[bh][k][d] -> vT[bh][d][k] ----------------
__global__ __launch_bounds__(256) void vtrans_kernel(const ushort_t* __restrict__ vh,
                                                     ushort_t* __restrict__ vT) {
    __shared__ ushort_t t[64][68];
    int bh = blockIdx.y;
    int k0 = blockIdx.x * 64;
    int tid = threadIdx.x;
    int r = tid >> 2, c0 = (tid & 3) * 16;
    const short8* src = (const short8*)&vh[((size_t)bh * 1024 + k0 + r) * 64 + c0];
    *(short8*)&t[r][c0] = src[0];
    *(short8*)&t[r][c0 + 8] = src[1];
    __syncthreads();
    ushort_t tmp[16];
    #pragma unroll
    for (int j = 0; j < 16; ++j) tmp[j] = t[c0 + j][r];
    short8* dst = (short8*)&vT[((size_t)bh * 64 + r) * 1024 + k0 + c0];
    dst[0] = *(short8*)&tmp[0];
    dst[1] = *(short8*)&tmp[8];
}

// ---------------- projection GEMM (global_load_lds, linear LDS) ----------------
// EPI 0: qU/qV (adds bq then U/V, layout (b,h,q,d))
// EPI 1: k/v proj (adds bias, layout (b,h,kk,d))
// EPI 2: R proj (no bias, layout (h,j,d));  a_mode=1: A may be f32 (scalar staging)
// EPI 3: out proj (adds bias, writes d_out (q,b,e), dtype per flag)
template<int EPI>
__global__ __launch_bounds__(256) void gemm_kernel(
    const void* Av, const ushort_t* BT, int M,
    const void* bias, const void* Up, const void* Vp,
    void* out0, void* out1, const int* flags, int a_mode) {
    __shared__ ushort_t As[4096];
    __shared__ ushort_t Bs[4096];
    const int f32m = flags[0];
    const int a_f32 = a_mode ? f32m : 0;
    const int tid = threadIdx.x;
    const int wid = tid >> 6, lane = tid & 63;
    const int wr = (wid >> 1) * 64, wc = (wid & 1) * 64;
    const int m0 = blockIdx.x * 128, n0 = blockIdx.y * 128;
    const int ch0 = wid * 2;
    const int lrow = lane >> 2, lcol = (lane & 3) * 8;

    f32x4 acc[4][4];
    #pragma unroll
    for (int m = 0; m < 4; ++m)
        #pragma unroll
        for (int n = 0; n < 4; ++n)
            acc[m][n] = (f32x4){0.f, 0.f, 0.f, 0.f};

    for (int k0 = 0; k0 < 1024; k0 += 32) {
        if (a_f32) {
            const float* Af = (const float*)Av + (size_t)(m0 + (tid >> 1)) * 1024 + k0 + (tid & 1) * 16;
            ushort_t* dst = &As[(tid >> 1) * 32 + (tid & 1) * 16];
            #pragma unroll
            for (int e = 0; e < 16; ++e) dst[e] = f2b(Af[e]);
        } else {
            #pragma unroll
            for (int t = 0; t < 2; ++t) {
                int ch = ch0 + t;
                const ushort_t* ga = (const ushort_t*)Av + (size_t)(m0 + ch * 16 + lrow) * 1024 + k0 + lcol;
                __builtin_amdgcn_global_load_lds((async_src_t*)ga, (async_dst_t*)&As[ch * 512], 16, 0, 0);
            }
        }
        #pragma unroll
        for (int t = 0; t < 2; ++t) {
            int ch = ch0 + t;
            const ushort_t* gb = BT + (size_t)(n0 + ch * 16 + lrow) * 1024 + k0 + lcol;
            __builtin_amdgcn_global_load_lds((async_src_t*)gb, (async_dst_t*)&Bs[ch * 512], 16, 0, 0);
        }
        __syncthreads();

        short8 af[4], bf[4];
        #pragma unroll
        for (int m = 0; m < 4; ++m)
            af[m] = *(const short8*)&As[(wr + m * 16 + (lane & 15)) * 32 + (lane >> 4) * 8];
        #pragma unroll
        for (int n = 0; n < 4; ++n)
            bf[n] = *(const short8*)&Bs[(wc + n * 16 + (lane & 15)) * 32 + (lane >> 4) * 8];
        #pragma unroll
        for (int m = 0; m < 4; ++m)
            #pragma unroll
            for (int n = 0; n < 4; ++n)
                acc[m][n] = MFMA16(af[m], bf[n], acc[m][n]);
        __syncthreads();
    }

    #pragma unroll
    for (int n = 0; n < 4; ++n) {
        int gn = n0 + wc + n * 16 + (lane & 15);
        float bv_ = (EPI == 2) ? 0.f : ldf(bias, gn, f32m);
        float uu = 0.f, vv = 0.f;
        if (EPI == 0) { uu = ldf(Up, gn, f32m); vv = ldf(Vp, gn, f32m); }
        #pragma unroll
        for (int m = 0; m < 4; ++m) {
            #pragma unroll
            for (int j = 0; j < 4; ++j) {
                int gm = m0 + wr + m * 16 + (lane >> 4) * 4 + j;
                float c = acc[m][n][j] + bv_;
                if (EPI == 0) {
                    int q = gm >> 3, b = gm & 7;
                    int h = gn >> 6, d = gn & 63;
                    int idx = ((b * 16 + h) * 512 + q) * 64 + d;
                    ((ushort_t*)out0)[idx] = f2b(c + uu);
                    ((ushort_t*)out1)[idx] = f2b(c + vv);
                } else if (EPI == 1) {
                    int kk = gm >> 3, b = gm & 7;
                    int h = gn >> 6, d = gn & 63;
                    ((ushort_t*)out0)[((b * 16 + h) * 1024 + kk) * 64 + d] = f2b(c);
                } else if (EPI == 2) {
                    int h = gn >> 6, d = gn & 63;
                    ((ushort_t*)out0)[(h * 1024 + gm) * 64 + d] = f2b(c);
                } else {
                    if (f32m) ((float*)out0)[gm * 1024 + gn] = c;
                    else ((ushort_t*)out0)[gm * 1024 + gn] = f2b(c);
                }
            }
        }
    }
}

// ---------------- fused attention (S^T layout, prefetched loads, 8 waves) ----------------
// block: 16 q-rows x one (b,h); 8 waves, wave w owns k in [w*128, w*128+128)
// Lane: c = lane&15 = q-column, g = lane>>4. S^T C-layout: col=c(q), row=k-local.
#define SP_STR 1032   // sPos row stride (ushorts): 516 words % 32 = 4 -> 2-way banks (free)
#define PB_STR 136    // sPb row stride (ushorts): 68 words % 32 = 4 -> 2-way banks (free)
__global__ __launch_bounds__(512, 4) void attn_kernel(
    const ushort_t* __restrict__ qU, const ushort_t* __restrict__ qV,
    const ushort_t* __restrict__ kh, const ushort_t* __restrict__ vT,
    const ushort_t* __restrict__ Rl, const void* __restrict__ mask,
    const void* __restrict__ pad, ushort_t* __restrict__ alpha, const int* flags) {

    // union region: sPos [17][1032] u16 (35,088 B) | sPb [8][16][136] u16 (34,816 B)
    //             | sO [8][1088] f32 (34,816 B). Aliasing is barrier-separated.
    __shared__ __align__(16) uchar_t uni[35104];
    ushort_t* sPos = (ushort_t*)uni;
    ushort_t* sPb  = (ushort_t*)uni;
    float*    sO   = (float*)uni;
    __shared__ float spad[512];
    __shared__ float sred[2][8][16];
    __shared__ float ssinv[16];

    const int tid = threadIdx.x;
    const int wid = tid >> 6, lane = tid & 63;
    const int g = lane >> 4, c = lane & 15;
    const int q0 = blockIdx.x * 16;
    const int bh = blockIdx.y;
    const int b = bh >> 4, h = bh & 15;
    const int f32m = flags[0], mm = flags[1];
    const int kbase = wid * 128;

    spad[tid & 511] = ldf(pad, b * 512 + (tid & 511), f32m);

    // ---- position: PR^T[j][q] = R[j] . qV[q];  prefetch ALL R loads, then MFMA
    {
        const ushort_t* qvap = qV + ((size_t)bh * 512 + q0 + c) * 64 + g * 8;
        short8 bva0 = *(const short8*)qvap;
        short8 bva1 = *(const short8*)(qvap + 32);
        int qvbq = q0 + 16 + c; if (qvbq > 511) qvbq = 511;
        const ushort_t* qvbp = qV + ((size_t)bh * 512 + qvbq) * 64 + g * 8;
        short8 bvb0 = *(const short8*)qvbp;
        short8 bvb1 = *(const short8*)(qvbp + 32);
        short8 ra[8][2];
        #pragma unroll
        for (int m = 0; m < 8; ++m) {
            const ushort_t* rp = Rl + ((size_t)h * 1024 + kbase + m * 16 + c) * 64 + g * 8;
            ra[m][0] = *(const short8*)rp;
            ra[m][1] = *(const short8*)(rp + 32);
        }
        #pragma unroll
        for (int m = 0; m < 8; ++m) {
            f32x4 p0 = (f32x4){0.f, 0.f, 0.f, 0.f};
            p0 = MFMA16(ra[m][0], bva0, p0);
            p0 = MFMA16(ra[m][1], bva1, p0);
            f32x4 p1 = (f32x4){0.f, 0.f, 0.f, 0.f};
            p1 = MFMA16(ra[m][0], bvb0, p1);
            p1 = MFMA16(ra[m][1], bvb1, p1);
            uint2 w;
            w.x = pk2(p0[0], p0[1]);
            w.y = pk2(p0[2], p0[3]);
            *(uint2*)&sPos[c * SP_STR + kbase + m * 16 + g * 4] = w;
            if (c == 0) {
                uint2 x;
                x.x = pk2(p1[0], p1[1]);
                x.y = pk2(p1[2], p1[3]);
                *(uint2*)&sPos[16 * SP_STR + kbase + m * 16 + g * 4] = x;
            }
        }
    }

    // ---- content: S^T[k][q] = K[k] . qU[q];  prefetch ALL K loads, then MFMA
    f32x4 acc[8];
    {
        const ushort_t* qup = qU + ((size_t)bh * 512 + q0 + c) * 64 + g * 8;
        short8 bu0 = *(const short8*)qup;
        short8 bu1 = *(const short8*)(qup + 32);
        short8 ka[8][2];
        #pragma unroll
        for (int m = 0; m < 8; ++m) {
            const ushort_t* kp = kh + ((size_t)bh * 1024 + kbase + m * 16 + c) * 64 + g * 8;
            ka[m][0] = *(const short8*)kp;
            ka[m][1] = *(const short8*)(kp + 32);
        }
        #pragma unroll
        for (int m = 0; m < 8; ++m) {
            f32x4 t = (f32x4){0.f, 0.f, 0.f, 0.f};
            t = MFMA16(ka[m][0], bu0, t);
            t = MFMA16(ka[m][1], bu1, t);
            acc[m] = t;
        }
    }
    __syncthreads();

    // ---- prefetch mask words for all 8 m
    const int q = q0 + c;
    uint_t mwr[8][4];
    if (mm == 1) {
        #pragma unroll
        for (int m = 0; m < 8; ++m) {
            int k0e = kbase + m * 16 + g * 4;
            uint_t w = *(const uint_t*)((const uchar_t*)mask + (size_t)q * 1024 + k0e);
            mwr[m][0] = w & 0xFFu; mwr[m][1] = w & 0xFF00u; mwr[m][2] = w & 0xFF0000u; mwr[m][3] = w & 0xFF000000u;
        }
    } else if (mm == 2) {
        #pragma unroll
        for (int m = 0; m < 8; ++m) {
            int k0e = kbase + m * 16 + g * 4;
            uint2 w = *(const uint2*)((const ushort_t*)mask + (size_t)q * 1024 + k0e);
            mwr[m][0] = w.x & 0xFFFFu; mwr[m][1] = w.x >> 16; mwr[m][2] = w.y & 0xFFFFu; mwr[m][3] = w.y >> 16;
        }
    } else {
        #pragma unroll
        for (int m = 0; m < 8; ++m) {
            int k0e = kbase + m * 16 + g * 4;
            uint4 w = *(const uint4*)((const uint_t*)mask + (size_t)q * 1024 + k0e);
            mwr[m][0] = w.x; mwr[m][1] = w.y; mwr[m][2] = w.z; mwr[m][3] = w.w;
        }
    }

    // ---- score: add rel-shifted position (sPos gather), scale, masks
    const float padq = spad[q];
    float mx = -3.0e38f;
    #pragma unroll
    for (int m = 0; m < 8; ++m) {
        int k0e = kbase + m * 16 + g * 4;
        #pragma unroll
        for (int jj = 0; jj < 4; ++jj) {
            int k = k0e + jj;
            int delta = k - q;
            int wrap = (delta > 512) ? 1 : 0;
            int j = wrap ? (delta - 514) : (delta + 511);
            float pos = b2f(sPos[(c + wrap) * SP_STR + (j < 0 ? 0 : j)]);
            if (delta == 513) pos = 0.f;
            float s = (acc[m][jj] + pos) * 0.03125f;
            bool dead = (mwr[m][jj] != 0);
            if (k >= 512) {
                float padk = spad[k - 512];
                if (padq == 0.f || padk == 0.f) dead = true;
            }
            if (dead) s = -1e20f;
            acc[m][jj] = s;
            mx = fmaxf(mx, s);
        }
    }
    // row-max: lanes sharing q are xor-16/32 apart; then cross-wave
    mx = fmaxf(mx, __shfl_xor(mx, 16, 64));
    mx = fmaxf(mx, __shfl_xor(mx, 32, 64));
    if (lane < 16) sred[0][wid][c] = mx;
    __syncthreads();   // also: all sPos reads complete before sPb overlays it
    {
        float a0 = fmaxf(fmaxf(sred[0][0][c], sred[0][1][c]), fmaxf(sred[0][2][c], sred[0][3][c]));
        float a1 = fmaxf(fmaxf(sred[0][4][c], sred[0][5][c]), fmaxf(sred[0][6][c], sred[0][7][c]));
        mx = fmaxf(a0, a1);
    }

    // ---- exp + pack P (bf16) into per-wave LDS tile sPb[wid][c][k_local]
    float ls = 0.f;
    #pragma unroll
    for (int m = 0; m < 8; ++m) {
        float p0 = __expf(acc[m][0] - mx);
        float p1 = __expf(acc[m][1] - mx);
        float p2 = __expf(acc[m][2] - mx);
        float p3 = __expf(acc[m][3] - mx);
        ls += (p0 + p1) + (p2 + p3);
        uint2 w;
        w.x = pk2(p0, p1);
        w.y = pk2(p2, p3);
        *(uint2*)&sPb[(wid * 16 + c) * PB_STR + m * 16 + g * 4] = w;
    }
    ls += __shfl_xor(ls, 16, 64);
    ls += __shfl_xor(ls, 32, 64);
    if (lane < 16) sred[1][wid][c] = ls;

    // ---- PV: prefetch ALL V loads while the ls-barrier settles
    short8 va[4][4];
    #pragma unroll
    for (int ch = 0; ch < 4; ++ch)
        #pragma unroll
        for (int dm = 0; dm < 4; ++dm)
            va[ch][dm] = *(const short8*)(vT + ((size_t)bh * 64 + dm * 16 + c) * 1024 + kbase + ch * 32 + g * 8);
    __syncthreads();   // sPb writes visible; all waves' P staged
    float ls2;
    {
        float a0 = (sred[1][0][c] + sred[1][1][c]) + (sred[1][2][c] + sred[1][3][c]);
        float a1 = (sred[1][4][c] + sred[1][5][c]) + (sred[1][6][c] + sred[1][7][c]);
        ls2 = a0 + a1;
    }
    if (wid == 0 && lane < 16) ssinv[c] = 1.0f / ls2;

    f32x4 oacc[4];
    #pragma unroll
    for (int dm = 0; dm < 4; ++dm) oacc[dm] = (f32x4){0.f, 0.f, 0.f, 0.f};
    short8 pbv[4];
    #pragma unroll
    for (int ch = 0; ch < 4; ++ch)
        pbv[ch] = *(const short8*)&sPb[(wid * 16 + c) * PB_STR + ch * 32 + g * 8];
    #pragma unroll
    for (int ch = 0; ch < 4; ++ch)
        #pragma unroll
        for (int dm = 0; dm < 4; ++dm)
            oacc[dm] = MFMA16(va[ch][dm], pbv[ch], oacc[dm]);

    // cross-wave O reduction (overlay sO on union region; PV sPb reads done)
    __syncthreads();
    #pragma unroll
    for (int dm = 0; dm < 4; ++dm)
        #pragma unroll
        for (int jj = 0; jj < 4; ++jj)
            sO[wid * 1088 + (dm * 16 + g * 4 + jj) * 17 + c] = oacc[dm][jj];
    __syncthreads();
    for (int e = tid; e < 1024; e += 512) {
        int d = e & 63, qq = e >> 6;
        float v = ((sO[d * 17 + qq] + sO[1088 + d * 17 + qq]) +
                   (sO[2176 + d * 17 + qq] + sO[3264 + d * 17 + qq])) +
                  ((sO[4352 + d * 17 + qq] + sO[5440 + d * 17 + qq]) +
                   (sO[6528 + d * 17 + qq] + sO[7616 + d * 17 + qq]));
        v *= ssinv[qq];
        alpha[((size_t)(q0 + qq) * 8 + b) * 1024 + h * 64 + d] = f2b(v);
    }
}

// ---------------- launcher ----------------
// Workspace: EXACTLY 88,081,408 bytes (round-3/6/7/8 proven footprint), r7 alias scheme.
extern "C" void kernel_launch(void* const* d_in, const int* in_sizes, int n_in,
                              void* d_out, int out_size, void* d_ws, size_t ws_size,
                              hipStream_t stream) {
    char* ws = (char*)d_ws;
    int* flags = (int*)ws;
    ushort_t* WqT   = (ushort_t*)(ws + 1024);
    ushort_t* WkT   = WqT + 1048576;
    ushort_t* WvT   = WkT + 1048576;
    ushort_t* WposT = WvT + 1048576;
    ushort_t* WoT   = WposT + 1048576;
    ushort_t* qUw   = WoT + 1048576;            // 4,194,304
    ushort_t* qVw   = qUw + 4194304;            // 4,194,304
    ushort_t* khw   = qVw + 4194304;            // 8,388,608
    ushort_t* Rlw   = khw + 8388608;            // 1,048,576
    ushort_t* R1    = Rlw + 1048576;            // 4,194,304
    ushort_t* R2    = R1 + 4194304;             // 8,388,608
    ushort_t* R3    = R2 + 8388608;             // 8,388,608
    // aliases (lifetime-disjoint, stream-ordered):
    ushort_t* qbf = R1;     // convert out -> read by qGEMM -> dead
    ushort_t* alw = R1;     // attn out -> read by outGEMM
    ushort_t* kbf = R2;     // convert out -> read by kGEMM -> dead
    ushort_t* vhw = R2;     // vGEMM out -> read by vtrans -> dead
    ushort_t* vbf = R3;     // convert out -> read by vGEMM -> dead
    ushort_t* vTw = R3;     // vtrans out -> read by attn

    detect_kernel<<<1, 256, 0, stream>>>(d_in[6], d_in[7], flags);
    // bulk input conversion to bf16 (query, key, value)
    convert_kernel<<<2048, 256, 0, stream>>>(d_in[0], qbf, 524288, flags);
    convert_kernel<<<4096, 256, 0, stream>>>(d_in[1], kbf, 1048576, flags);
    convert_kernel<<<4096, 256, 0, stream>>>(d_in[2], vbf, 1048576, flags);
    // weight transposes
    transpose_kernel<<<dim3(32, 32, 5), dim3(32, 8), 0, stream>>>(
        d_in[8], d_in[10], d_in[12], d_in[14], d_in[15],
        WqT, WkT, WvT, WposT, WoT, flags);
    // q projection -> qU, qV (fast A path)
    gemm_kernel<0><<<dim3(32, 8), 256, 0, stream>>>(qbf, WqT, 4096, d_in[9], d_in[4], d_in[5], qUw, qVw, flags, 0);
    // k, v projections (fast A path)
    gemm_kernel<1><<<dim3(64, 8), 256, 0, stream>>>(kbf, WkT, 8192, d_in[11], nullptr, nullptr, khw, nullptr, flags, 0);
    gemm_kernel<1><<<dim3(64, 8), 256, 0, stream>>>(vbf, WvT, 8192, d_in[13], nullptr, nullptr, vhw, nullptr, flags, 0);
    // R projection (raw pos_embedding, scalar-convert staging when f32)
    gemm_kernel<2><<<dim3(8, 8), 256, 0, stream>>>(d_in[3], WposT, 1024, nullptr, nullptr, nullptr, Rlw, nullptr, flags, 1);
    // V transpose for PV A-operand: R2 -> R3
    vtrans_kernel<<<dim3(16, 128), 256, 0, stream>>>(vhw, vTw);
    // fused attention (8 waves/block, prefetched loads)
    attn_kernel<<<dim3(32, 128), 512, 0, stream>>>(qUw, qVw, khw, vTw, Rlw, d_in[6], d_in[7], alw, flags);
    // output projection
    gemm_kernel<3><<<dim3(32, 8), 256, 0, stream>>>(alw, WoT, 4096, d_in[16], nullptr, nullptr, d_out, nullptr, flags, 0);
}